// Round 7
// baseline (480.970 us; speedup 1.0000x reference)
//
#include <hip/hip_runtime.h>
#include <hip/hip_bf16.h>
#include <math.h>

#define C_   128
#define HW_  4096
#define OC_  100
#define NSTAT_ 32768.0f

typedef __bf16 bf16x8 __attribute__((ext_vector_type(8)));
typedef __bf16 bf16x4 __attribute__((ext_vector_type(4)));
typedef float  f32x4  __attribute__((ext_vector_type(4)));

// ---------------- K1: 1x1 conv via MFMA bf16 -> t1c[b][px][64] bf16 + stats + wprep --------
// grid 512 = b(8) x chunk(64 of 64px); 256 thr = 4 waves, wave = one 16-px m-tile, N=64.
__global__ __launch_bounds__(256, 4) void k_conv1(const float* __restrict__ x,
                                                  const float* __restrict__ w,
                                                  const float* __restrict__ wenc,
                                                  __bf16* __restrict__ t1c,
                                                  float* __restrict__ csum,
                                                  float* __restrict__ csq,
                                                  __bf16* __restrict__ wprep) {
    __shared__ __bf16 xt[64 * 128];   // [px][ic], 256B rows, 16B-block XOR swizzle
    __shared__ __bf16 wt[64 * 128];   // [oc][ic], same swizzle
    __shared__ float sS[64], sQ[64];

    int blk = blockIdx.x;
    int b = blk & 7;
    int chunk = blk >> 3;             // 0..63
    int px0 = chunk * 64;
    int tid = threadIdx.x;
    if (tid < 64) { sS[tid] = 0.f; sQ[tid] = 0.f; }

    // pack enc weights -> wprep[oc 112][k 576], k = tap*64+ic  (blocks 0..62, 1024 each)
    if (blk < 63) {
#pragma unroll
        for (int u = 0; u < 4; ++u) {
            int idx = blk * 1024 + u * 256 + tid;   // < 64512 = 112*576
            int oc = idx / 576, k = idx - oc * 576;
            int tap = k >> 6, ic = k & 63;
            wprep[idx] = (oc < OC_) ? (__bf16)wenc[((size_t)oc * 64 + ic) * 9 + tap]
                                    : (__bf16)0.f;
        }
    }

    // stage comp_w (64 oc x 128 ic fp32) -> wt bf16: 2048 float4 jobs (FIX: was 512)
#pragma unroll
    for (int it = 0; it < 8; ++it) {
        int j = it * 256 + tid;       // 0..2047
        int oc = j >> 5, f = j & 31;
        float4 v = *(const float4*)(w + (size_t)oc * 128 + f * 4);
        int blki = (f >> 1) ^ (oc & 15);
        bf16x4 st;
        st[0] = (__bf16)v.x; st[1] = (__bf16)v.y; st[2] = (__bf16)v.z; st[3] = (__bf16)v.w;
        *(bf16x4*)&wt[oc * 128 + blki * 8 + (f & 1) * 4] = st;
    }
    // stage x tile (64 px x 128 ic) -> xt bf16 (transpose 4x4 in regs), 512 jobs x 16 floats
#pragma unroll
    for (int it = 0; it < 2; ++it) {
        int j = it * 256 + tid;
        int px4 = (j & 15) * 4, icq = j >> 4;   // icq 0..31
        const float* xp = x + ((size_t)b * C_ + icq * 4) * HW_ + px0 + px4;
        float4 v0 = *(const float4*)(xp);
        float4 v1 = *(const float4*)(xp + HW_);
        float4 v2 = *(const float4*)(xp + 2 * HW_);
        float4 v3 = *(const float4*)(xp + 3 * HW_);
        float r0[4] = {v0.x, v0.y, v0.z, v0.w};
        float r1[4] = {v1.x, v1.y, v1.z, v1.w};
        float r2_[4] = {v2.x, v2.y, v2.z, v2.w};
        float r3[4] = {v3.x, v3.y, v3.z, v3.w};
#pragma unroll
        for (int r2 = 0; r2 < 4; ++r2) {
            int px = px4 + r2;
            int blki = (icq >> 1) ^ (px & 15);
            bf16x4 st;
            st[0] = (__bf16)r0[r2]; st[1] = (__bf16)r1[r2];
            st[2] = (__bf16)r2_[r2]; st[3] = (__bf16)r3[r2];
            *(bf16x4*)&xt[px * 128 + blki * 8 + (icq & 1) * 4] = st;
        }
    }
    __syncthreads();

    int lane = tid & 63, wv = tid >> 6;
    int p = lane & 15, q = lane >> 4;

    f32x4 acc[4];
#pragma unroll
    for (int n = 0; n < 4; ++n) acc[n] = (f32x4){0.f, 0.f, 0.f, 0.f};

#pragma unroll
    for (int kk = 0; kk < 4; ++kk) {
        int blki = (kk * 4 + q) ^ p;
        bf16x8 a = *(const bf16x8*)&xt[(wv * 16 + p) * 128 + blki * 8];
#pragma unroll
        for (int n = 0; n < 4; ++n) {
            bf16x8 bb = *(const bf16x8*)&wt[(n * 16 + p) * 128 + blki * 8];
            acc[n] = __builtin_amdgcn_mfma_f32_16x16x32_bf16(a, bb, acc[n], 0, 0, 0);
        }
    }

    // D: col(oc within tile) = p, row(px within tile) = q*4+rg
    __bf16* t1b = t1c + ((size_t)b * HW_ + px0 + wv * 16) * 64;
#pragma unroll
    for (int n = 0; n < 4; ++n) {
        float s = 0.f, qq = 0.f;
#pragma unroll
        for (int rg = 0; rg < 4; ++rg) {
            float v = acc[n][rg];
            t1b[(size_t)(q * 4 + rg) * 64 + n * 16 + p] = (__bf16)v;
            s += v; qq += v * v;
        }
        s += __shfl_down(s, 32, 64);  s += __shfl_down(s, 16, 64);
        qq += __shfl_down(qq, 32, 64); qq += __shfl_down(qq, 16, 64);
        if (lane < 16) {
            atomicAdd(&sS[n * 16 + p], s);
            atomicAdd(&sQ[n * 16 + p], qq);
        }
    }
    __syncthreads();
    if (tid < 64) {
        atomicAdd(&csum[tid], sS[tid]);
        atomicAdd(&csq[tid], sQ[tid]);
    }
}

// ---------------- K2: 3x3 conv MFMA bf16, inline BN1 finalize, partial BN2 stats -----------
__global__ __launch_bounds__(256, 4) void k_conv3(const __bf16* __restrict__ t1c,
                                                  const __bf16* __restrict__ wprep,
                                                  const float* __restrict__ csum,
                                                  const float* __restrict__ csq,
                                                  const float* __restrict__ cg,
                                                  const float* __restrict__ cb,
                                                  float* __restrict__ t2c,
                                                  float* __restrict__ esum,
                                                  float* __restrict__ esq) {
    __shared__ __bf16 xt[10 * 10 * 72];
    __shared__ float lsc[64], lsh[64];
    __shared__ float esuml[112], esql[112];

    int blk = blockIdx.x;
    int b = blk & 7;
    int tile = blk >> 3;
    int ty0 = (tile >> 3) * 8, tx0 = (tile & 7) * 8;
    int tid = threadIdx.x;
    if (tid < 112) { esuml[tid] = 0.f; esql[tid] = 0.f; }
    if (tid >= 128 && tid < 192) {
        int c = tid - 128;
        float invN = 1.0f / NSTAT_;
        float m = csum[c] * invN;
        float v = csq[c] * invN - m * m;
        float rs = rsqrtf(v + 1e-5f);
        float sc = cg[c] * rs;
        lsc[c] = sc;
        lsh[c] = cb[c] - m * sc;
    }
    __syncthreads();

    const __bf16* tb = t1c + (size_t)b * HW_ * 64;
#pragma unroll
    for (int it = 0; it < 7; ++it) {
        int idx = it * 256 + tid;
        if (idx < 1600) {
            int pxi = idx >> 4, f4 = idx & 15;
            int yy = pxi / 10, xx = pxi - yy * 10;
            int gy = ty0 + yy - 1, gx = tx0 + xx - 1;
            float o0 = 0.f, o1 = 0.f, o2 = 0.f, o3 = 0.f;
            if (gy >= 0 && gy < 64 && gx >= 0 && gx < 64) {
                bf16x4 v = *(const bf16x4*)(tb + ((size_t)(gy << 6) + gx) * 64 + f4 * 4);
                float4 sc = *(const float4*)(lsc + f4 * 4);
                float4 sh = *(const float4*)(lsh + f4 * 4);
                float u;
                u = fmaf((float)v[0], sc.x, sh.x); o0 = u / (1.f + __expf(-u));
                u = fmaf((float)v[1], sc.y, sh.y); o1 = u / (1.f + __expf(-u));
                u = fmaf((float)v[2], sc.z, sh.z); o2 = u / (1.f + __expf(-u));
                u = fmaf((float)v[3], sc.w, sh.w); o3 = u / (1.f + __expf(-u));
            }
            bf16x4 st;
            st[0] = (__bf16)o0; st[1] = (__bf16)o1; st[2] = (__bf16)o2; st[3] = (__bf16)o3;
            *(bf16x4*)&xt[pxi * 72 + f4 * 4] = st;
        }
    }
    __syncthreads();

    int lane = tid & 63, wv = tid >> 6;
    int p = lane & 15, q = lane >> 4;
    int ya = 2 * wv + (p >> 3), xa = p & 7;

    f32x4 acc[7];
#pragma unroll
    for (int n = 0; n < 7; ++n) acc[n] = (f32x4){0.f, 0.f, 0.f, 0.f};

#pragma unroll
    for (int kk = 0; kk < 18; ++kk) {
        const int tap = kk >> 1, ich = (kk & 1) * 32;
        const int ky = tap / 3, kx = tap - ky * 3;
        bf16x8 a0 = *(const bf16x8*)&xt[((ya + ky) * 10 + xa + kx) * 72 + ich + q * 8];
#pragma unroll
        for (int n = 0; n < 7; ++n) {
            bf16x8 bb = *(const bf16x8*)(wprep + ((size_t)(n * 16 + p)) * 576 + kk * 32 + q * 8);
            acc[n] = __builtin_amdgcn_mfma_f32_16x16x32_bf16(a0, bb, acc[n], 0, 0, 0);
        }
    }

    float* t2b = t2c + (size_t)b * HW_ * 112;
#pragma unroll
    for (int n = 0; n < 7; ++n) {
        float s = 0.f, qq = 0.f;
#pragma unroll
        for (int rg = 0; rg < 4; ++rg) {
            int mp = q * 4 + rg;
            int y = ty0 + 2 * wv + (mp >> 3), xo = tx0 + (mp & 7);
            float v = acc[n][rg];
            t2b[((size_t)y * 64 + xo) * 112 + n * 16 + p] = v;
            s += v; qq += v * v;
        }
        s += __shfl_down(s, 32, 64);  s += __shfl_down(s, 16, 64);
        qq += __shfl_down(qq, 32, 64); qq += __shfl_down(qq, 16, 64);
        if (lane < 16) {
            atomicAdd(&esuml[n * 16 + lane], s);
            atomicAdd(&esql[n * 16 + lane], qq);
        }
    }
    __syncthreads();
    if (tid < 112) {
        atomicAdd(&esum[tid], esuml[tid]);
        atomicAdd(&esq[tid], esql[tid]);
    }
}

// ---------------- K3: BN2 + softmax + reassembly; thread = hires pair x 16ch/stage ---------
// grid 1024 = b(8) x tile(64: 4tx x 16ty of 16x4 lowres) x chalf(2 of 64ch).
__global__ __launch_bounds__(256, 4) void k_carafe(const float* __restrict__ x,
                                                   const float* __restrict__ t2c,
                                                   const float* __restrict__ esum,
                                                   const float* __restrict__ esq,
                                                   const float* __restrict__ eg,
                                                   const float* __restrict__ eb,
                                                   float* __restrict__ out) {
    __shared__ float xt[160 * 32];    // [halo px 8x20][32 ch], 16B-block XOR swizzle
    __shared__ float esc[112], esh[112];

    int blk = blockIdx.x;
    int b = blk & 7;
    int r = blk >> 3;
    int tile = r & 63;
    int chalf = r >> 6;
    int tx0 = (tile & 3) * 16, ty0 = (tile >> 2) * 4;
    int tid = threadIdx.x;
    if (tid < 112) {
        float invN = 1.0f / NSTAT_;
        float m = esum[tid] * invN;
        float v = esq[tid] * invN - m * m;
        float rs = rsqrtf(v + 1e-5f);
        float sc = (tid < OC_) ? eg[tid] * rs : 0.f;
        esc[tid] = sc;
        esh[tid] = (tid < OC_) ? eb[tid] - m * sc : 0.f;
    }
    __syncthreads();

    int pid = tid & 127, half16 = tid >> 7;
    int prow = pid >> 4, pcol = pid & 15;     // 8 hires rows x 16 pairs
    int iy = ty0 + (prow >> 1), jx = tx0 + pcol;
    int s0 = (prow & 1) * 2;
    int ty = prow >> 1, txl = pcol;

    // softmax for the horizontal subpixel pair (s0, s0+1) — shared 25 taps
    float wgt[2][25];
    {
        const float* t2p = t2c + ((size_t)((b << 12) + (iy << 6) + jx)) * 112 + s0;
        float mx0 = -1e30f, mx1 = -1e30f;
#pragma unroll
        for (int k = 0; k < 25; ++k) {
            float2 lv = *(const float2*)(t2p + k * 4);
            float l0 = fmaf(lv.x, esc[4 * k + s0], esh[4 * k + s0]);
            float l1 = fmaf(lv.y, esc[4 * k + s0 + 1], esh[4 * k + s0 + 1]);
            wgt[0][k] = l0; wgt[1][k] = l1;
            mx0 = fmaxf(mx0, l0); mx1 = fmaxf(mx1, l1);
        }
        float mxs[2] = {mx0, mx1};
#pragma unroll
        for (int s = 0; s < 2; ++s) {
            float sum = 0.f;
#pragma unroll
            for (int k = 0; k < 25; ++k) {
                float e = __expf(wgt[s][k] - mxs[s]);
                wgt[s][k] = e;
                sum += e;
            }
            float inv = 1.f / sum;
#pragma unroll
            for (int k = 0; k < 25; ++k) wgt[s][k] *= inv;
        }
    }

    const float* xb = x + (size_t)b * C_ * HW_;
    float* op = out + (size_t)b * C_ * 16384 + (size_t)(ty0 * 2 + prow) * 128 + tx0 * 2 + pcol * 2;

    for (int s32 = 0; s32 < 2; ++s32) {
        int cbase = chalf * 64 + s32 * 32;
        __syncthreads();
        // stage 160 halo px x 32 ch fp32 (1280 float4 jobs)
#pragma unroll
        for (int it = 0; it < 5; ++it) {
            int idx = it * 256 + tid;
            int c4 = idx / 160;
            int r2 = idx - c4 * 160;
            int yy = r2 / 20, xx = r2 - yy * 20;
            int gy = ty0 - 2 + yy, gx = tx0 - 2 + xx;
            float v0 = 0.f, v1 = 0.f, v2 = 0.f, v3 = 0.f;
            if (gy >= 0 && gy < 64 && gx >= 0 && gx < 64) {
                size_t base = (size_t)(cbase + c4 * 4) * HW_ + (gy << 6) + gx;
                v0 = xb[base];
                v1 = xb[base + HW_];
                v2 = xb[base + 2 * HW_];
                v3 = xb[base + 3 * HW_];
            }
            float* d = &xt[r2 * 32 + ((c4 ^ (r2 & 7)) << 2)];
            d[0] = v0; d[1] = v1; d[2] = v2; d[3] = v3;
        }
        __syncthreads();

        float acc0[16], acc1[16];
#pragma unroll
        for (int e = 0; e < 16; ++e) { acc0[e] = 0.f; acc1[e] = 0.f; }

#pragma unroll
        for (int dy = 0; dy < 5; ++dy)
#pragma unroll
            for (int dx = 0; dx < 5; ++dx) {
                int pxi = (ty + dy) * 20 + txl + dx;
                float w0 = wgt[0][dy * 5 + dx];
                float w1 = wgt[1][dy * 5 + dx];
#pragma unroll
                for (int cc = 0; cc < 4; ++cc) {
                    int c4 = half16 * 4 + cc;
                    f32x4 xv = *(const f32x4*)&xt[pxi * 32 + ((c4 ^ (pxi & 7)) << 2)];
#pragma unroll
                    for (int e = 0; e < 4; ++e) {
                        acc0[cc * 4 + e] = fmaf(w0, xv[e], acc0[cc * 4 + e]);
                        acc1[cc * 4 + e] = fmaf(w1, xv[e], acc1[cc * 4 + e]);
                    }
                }
            }
#pragma unroll
        for (int e = 0; e < 16; ++e) {
            int ch = cbase + half16 * 16 + e;
            float2 st; st.x = acc0[e]; st.y = acc1[e];
            *(float2*)(op + (size_t)ch * 16384) = st;
        }
    }
}

extern "C" void kernel_launch(void* const* d_in, const int* in_sizes, int n_in,
                              void* d_out, int out_size, void* d_ws, size_t ws_size,
                              hipStream_t stream) {
    const float* x      = (const float*)d_in[0];
    const float* comp_w = (const float*)d_in[1];
    const float* comp_g = (const float*)d_in[2];
    const float* comp_b = (const float*)d_in[3];
    const float* enc_w  = (const float*)d_in[4];
    const float* enc_g  = (const float*)d_in[5];
    const float* enc_b  = (const float*)d_in[6];
    float* out = (float*)d_out;

    float* ws = (float*)d_ws;
    __bf16* t1c = (__bf16*)ws;             // 8*4096*64 bf16 = 4 MB
    float* t2c  = ws + 1048576;            // 8*4096*112 fp32 = 14.7 MB
    float* st   = ws + 1048576 + 3670016;
    float* csum = st;                      // 64
    float* csq  = st + 64;                 // 64
    float* esum = st + 128;                // 112
    float* esq  = st + 240;                // 112
    __bf16* wprep = (__bf16*)(st + 352);   // 112*576 bf16

    hipMemsetAsync(st, 0, 352 * sizeof(float), stream);
    k_conv1<<<512, 256, 0, stream>>>(x, comp_w, enc_w, t1c, csum, csq, wprep);
    k_conv3<<<512, 256, 0, stream>>>(t1c, wprep, csum, csq, comp_g, comp_b, t2c, esum, esq);
    k_carafe<<<1024, 256, 0, stream>>>(x, t2c, esum, esq, enc_g, enc_b, out);
}

// Round 8
// 178.487 us; speedup vs baseline: 2.6947x; 2.6947x over previous
//
#include <hip/hip_runtime.h>
#include <hip/hip_bf16.h>
#include <math.h>

#define C_   128
#define HW_  4096
#define OC_  100
#define NSTAT_ 32768.0f

typedef __bf16 bf16x8 __attribute__((ext_vector_type(8)));
typedef __bf16 bf16x4 __attribute__((ext_vector_type(4)));
typedef float  f32x4  __attribute__((ext_vector_type(4)));

// ---------------- K1: 1x1 conv via MFMA bf16 -> t1c[b][px][64] bf16 + stats + wprep --------
// grid 512 = b(8) x chunk(64 of 64px); 256 thr = 4 waves, wave = one 16-px m-tile, N=64.
__global__ __launch_bounds__(256, 4) void k_conv1(const float* __restrict__ x,
                                                  const float* __restrict__ w,
                                                  const float* __restrict__ wenc,
                                                  __bf16* __restrict__ t1c,
                                                  float* __restrict__ csum,
                                                  float* __restrict__ csq,
                                                  __bf16* __restrict__ wprep) {
    __shared__ __bf16 xt[64 * 128];   // [px][ic], 256B rows, 16B-block XOR swizzle
    __shared__ __bf16 wt[64 * 128];   // [oc][ic], same swizzle
    __shared__ float sS[64], sQ[64];

    int blk = blockIdx.x;
    int b = blk & 7;
    int chunk = blk >> 3;             // 0..63
    int px0 = chunk * 64;
    int tid = threadIdx.x;
    if (tid < 64) { sS[tid] = 0.f; sQ[tid] = 0.f; }

    // pack enc weights -> wprep[oc 112][k 576], k = tap*64+ic  (blocks 0..62, 1024 each)
    if (blk < 63) {
#pragma unroll
        for (int u = 0; u < 4; ++u) {
            int idx = blk * 1024 + u * 256 + tid;   // < 64512 = 112*576
            int oc = idx / 576, k = idx - oc * 576;
            int tap = k >> 6, ic = k & 63;
            wprep[idx] = (oc < OC_) ? (__bf16)wenc[((size_t)oc * 64 + ic) * 9 + tap]
                                    : (__bf16)0.f;
        }
    }

    // stage comp_w (64 oc x 128 ic fp32) -> wt bf16: 2048 float4 jobs
#pragma unroll
    for (int it = 0; it < 8; ++it) {
        int j = it * 256 + tid;       // 0..2047
        int oc = j >> 5, f = j & 31;
        float4 v = *(const float4*)(w + (size_t)oc * 128 + f * 4);
        int blki = (f >> 1) ^ (oc & 15);
        bf16x4 st;
        st[0] = (__bf16)v.x; st[1] = (__bf16)v.y; st[2] = (__bf16)v.z; st[3] = (__bf16)v.w;
        *(bf16x4*)&wt[oc * 128 + blki * 8 + (f & 1) * 4] = st;
    }
    // stage x tile (64 px x 128 ic) -> xt bf16 (transpose 4x4 in regs), 512 jobs x 16 floats
#pragma unroll
    for (int it = 0; it < 2; ++it) {
        int j = it * 256 + tid;
        int px4 = (j & 15) * 4, icq = j >> 4;   // icq 0..31
        const float* xp = x + ((size_t)b * C_ + icq * 4) * HW_ + px0 + px4;
        float4 v0 = *(const float4*)(xp);
        float4 v1 = *(const float4*)(xp + HW_);
        float4 v2 = *(const float4*)(xp + 2 * HW_);
        float4 v3 = *(const float4*)(xp + 3 * HW_);
        float r0[4] = {v0.x, v0.y, v0.z, v0.w};
        float r1[4] = {v1.x, v1.y, v1.z, v1.w};
        float r2_[4] = {v2.x, v2.y, v2.z, v2.w};
        float r3[4] = {v3.x, v3.y, v3.z, v3.w};
#pragma unroll
        for (int r2 = 0; r2 < 4; ++r2) {
            int px = px4 + r2;
            int blki = (icq >> 1) ^ (px & 15);
            bf16x4 st;
            st[0] = (__bf16)r0[r2]; st[1] = (__bf16)r1[r2];
            st[2] = (__bf16)r2_[r2]; st[3] = (__bf16)r3[r2];
            *(bf16x4*)&xt[px * 128 + blki * 8 + (icq & 1) * 4] = st;
        }
    }
    __syncthreads();

    int lane = tid & 63, wv = tid >> 6;
    int p = lane & 15, q = lane >> 4;

    f32x4 acc[4];
#pragma unroll
    for (int n = 0; n < 4; ++n) acc[n] = (f32x4){0.f, 0.f, 0.f, 0.f};

#pragma unroll
    for (int kk = 0; kk < 4; ++kk) {
        int blki = (kk * 4 + q) ^ p;
        bf16x8 a = *(const bf16x8*)&xt[(wv * 16 + p) * 128 + blki * 8];
#pragma unroll
        for (int n = 0; n < 4; ++n) {
            bf16x8 bb = *(const bf16x8*)&wt[(n * 16 + p) * 128 + blki * 8];
            acc[n] = __builtin_amdgcn_mfma_f32_16x16x32_bf16(a, bb, acc[n], 0, 0, 0);
        }
    }

    // D: col(oc within tile) = p, row(px within tile) = q*4+rg
    __bf16* t1b = t1c + ((size_t)b * HW_ + px0 + wv * 16) * 64;
#pragma unroll
    for (int n = 0; n < 4; ++n) {
        float s = 0.f, qq = 0.f;
#pragma unroll
        for (int rg = 0; rg < 4; ++rg) {
            float v = acc[n][rg];
            t1b[(size_t)(q * 4 + rg) * 64 + n * 16 + p] = (__bf16)v;
            s += v; qq += v * v;
        }
        s += __shfl_down(s, 32, 64);  s += __shfl_down(s, 16, 64);
        qq += __shfl_down(qq, 32, 64); qq += __shfl_down(qq, 16, 64);
        if (lane < 16) {
            atomicAdd(&sS[n * 16 + p], s);
            atomicAdd(&sQ[n * 16 + p], qq);
        }
    }
    __syncthreads();
    if (tid < 64) {
        atomicAdd(&csum[tid], sS[tid]);
        atomicAdd(&csq[tid], sQ[tid]);
    }
}

// ---------------- K2: 3x3 conv MFMA bf16, inline BN1 finalize, partial BN2 stats -----------
__global__ __launch_bounds__(256, 4) void k_conv3(const __bf16* __restrict__ t1c,
                                                  const __bf16* __restrict__ wprep,
                                                  const float* __restrict__ csum,
                                                  const float* __restrict__ csq,
                                                  const float* __restrict__ cg,
                                                  const float* __restrict__ cb,
                                                  float* __restrict__ t2c,
                                                  float* __restrict__ esum,
                                                  float* __restrict__ esq) {
    __shared__ __bf16 xt[10 * 10 * 72];
    __shared__ float lsc[64], lsh[64];
    __shared__ float esuml[112], esql[112];

    int blk = blockIdx.x;
    int b = blk & 7;
    int tile = blk >> 3;
    int ty0 = (tile >> 3) * 8, tx0 = (tile & 7) * 8;
    int tid = threadIdx.x;
    if (tid < 112) { esuml[tid] = 0.f; esql[tid] = 0.f; }
    if (tid >= 128 && tid < 192) {
        int c = tid - 128;
        float invN = 1.0f / NSTAT_;
        float m = csum[c] * invN;
        float v = csq[c] * invN - m * m;
        float rs = rsqrtf(v + 1e-5f);
        float sc = cg[c] * rs;
        lsc[c] = sc;
        lsh[c] = cb[c] - m * sc;
    }
    __syncthreads();

    const __bf16* tb = t1c + (size_t)b * HW_ * 64;
#pragma unroll
    for (int it = 0; it < 7; ++it) {
        int idx = it * 256 + tid;
        if (idx < 1600) {
            int pxi = idx >> 4, f4 = idx & 15;
            int yy = pxi / 10, xx = pxi - yy * 10;
            int gy = ty0 + yy - 1, gx = tx0 + xx - 1;
            float o0 = 0.f, o1 = 0.f, o2 = 0.f, o3 = 0.f;
            if (gy >= 0 && gy < 64 && gx >= 0 && gx < 64) {
                bf16x4 v = *(const bf16x4*)(tb + ((size_t)(gy << 6) + gx) * 64 + f4 * 4);
                float4 sc = *(const float4*)(lsc + f4 * 4);
                float4 sh = *(const float4*)(lsh + f4 * 4);
                float u;
                u = fmaf((float)v[0], sc.x, sh.x); o0 = u / (1.f + __expf(-u));
                u = fmaf((float)v[1], sc.y, sh.y); o1 = u / (1.f + __expf(-u));
                u = fmaf((float)v[2], sc.z, sh.z); o2 = u / (1.f + __expf(-u));
                u = fmaf((float)v[3], sc.w, sh.w); o3 = u / (1.f + __expf(-u));
            }
            bf16x4 st;
            st[0] = (__bf16)o0; st[1] = (__bf16)o1; st[2] = (__bf16)o2; st[3] = (__bf16)o3;
            *(bf16x4*)&xt[pxi * 72 + f4 * 4] = st;
        }
    }
    __syncthreads();

    int lane = tid & 63, wv = tid >> 6;
    int p = lane & 15, q = lane >> 4;
    int ya = 2 * wv + (p >> 3), xa = p & 7;

    f32x4 acc[7];
#pragma unroll
    for (int n = 0; n < 7; ++n) acc[n] = (f32x4){0.f, 0.f, 0.f, 0.f};

#pragma unroll
    for (int kk = 0; kk < 18; ++kk) {
        const int tap = kk >> 1, ich = (kk & 1) * 32;
        const int ky = tap / 3, kx = tap - ky * 3;
        bf16x8 a0 = *(const bf16x8*)&xt[((ya + ky) * 10 + xa + kx) * 72 + ich + q * 8];
#pragma unroll
        for (int n = 0; n < 7; ++n) {
            bf16x8 bb = *(const bf16x8*)(wprep + ((size_t)(n * 16 + p)) * 576 + kk * 32 + q * 8);
            acc[n] = __builtin_amdgcn_mfma_f32_16x16x32_bf16(a0, bb, acc[n], 0, 0, 0);
        }
    }

    float* t2b = t2c + (size_t)b * HW_ * 112;
#pragma unroll
    for (int n = 0; n < 7; ++n) {
        float s = 0.f, qq = 0.f;
#pragma unroll
        for (int rg = 0; rg < 4; ++rg) {
            int mp = q * 4 + rg;
            int y = ty0 + 2 * wv + (mp >> 3), xo = tx0 + (mp & 7);
            float v = acc[n][rg];
            t2b[((size_t)y * 64 + xo) * 112 + n * 16 + p] = v;
            s += v; qq += v * v;
        }
        s += __shfl_down(s, 32, 64);  s += __shfl_down(s, 16, 64);
        qq += __shfl_down(qq, 32, 64); qq += __shfl_down(qq, 16, 64);
        if (lane < 16) {
            atomicAdd(&esuml[n * 16 + lane], s);
            atomicAdd(&esql[n * 16 + lane], qq);
        }
    }
    __syncthreads();
    if (tid < 112) {
        atomicAdd(&esum[tid], esuml[tid]);
        atomicAdd(&esq[tid], esql[tid]);
    }
}

// ---------------- K3: BN2 + softmax + reassembly; LOW register version (no spill) ----------
// grid 512 = b(8) x tile(64: 4 of 16w x 16 of 4t lowres); 256 thr = 64 px x 4 subpixels.
// Thread state: wgt[25] + acc[16] (~56 VGPR). 8 channel-stages of 16 ch in LDS (pad 20).
__global__ __launch_bounds__(256, 4) void k_carafe(const float* __restrict__ x,
                                                   const float* __restrict__ t2c,
                                                   const float* __restrict__ esum,
                                                   const float* __restrict__ esq,
                                                   const float* __restrict__ eg,
                                                   const float* __restrict__ eb,
                                                   float* __restrict__ out) {
    __shared__ float xt[160 * 20];    // [halo px 8x20][16 ch pad 20] = 12800 B
    __shared__ float esc[112], esh[112];

    int blk = blockIdx.x;
    int b = blk & 7;
    int tile = blk >> 3;              // 0..63
    int tx0 = (tile & 3) * 16, ty0 = (tile >> 2) * 4;
    int tid = threadIdx.x;
    if (tid < 112) {
        float invN = 1.0f / NSTAT_;
        float m = esum[tid] * invN;
        float v = esq[tid] * invN - m * m;
        float rs = rsqrtf(v + 1e-5f);
        float sc = (tid < OC_) ? eg[tid] * rs : 0.f;
        esc[tid] = sc;
        esh[tid] = (tid < OC_) ? eb[tid] - m * sc : 0.f;
    }
    __syncthreads();

    int s = tid & 3, px = tid >> 2;   // px 0..63
    int pxx = px & 15, py = px >> 4;  // 16 wide x 4 tall lowres
    int iy = ty0 + py, jx = tx0 + pxx;

    // softmax over this subpixel's 25 taps (4 lanes read 4 consecutive floats -> dense)
    float wgt[25];
    {
        const float* t2p = t2c + ((size_t)((b << 12) + (iy << 6) + jx)) * 112 + s;
        float mx = -1e30f;
#pragma unroll
        for (int k = 0; k < 25; ++k) {
            float l = fmaf(t2p[k * 4], esc[4 * k + s], esh[4 * k + s]);
            wgt[k] = l;
            mx = fmaxf(mx, l);
        }
        float sum = 0.f;
#pragma unroll
        for (int k = 0; k < 25; ++k) {
            float e = __expf(wgt[k] - mx);
            wgt[k] = e;
            sum += e;
        }
        float inv = 1.f / sum;
#pragma unroll
        for (int k = 0; k < 25; ++k) wgt[k] *= inv;
    }

    const float* xb = x + (size_t)b * C_ * HW_;
    // output px for this thread: full-line writes (wave = 16 px x 4 subpx = 2 x 128B lines)
    int i0 = iy * 2 + (s >> 1), j0 = jx * 2 + (s & 1);
    float* op = out + (size_t)b * C_ * 16384 + (size_t)i0 * 128 + j0;

    for (int stage = 0; stage < 8; ++stage) {
        int cbase = stage * 16;
        __syncthreads();
        // stage 160 halo px x 16 ch (640 f32x4 jobs)
#pragma unroll
        for (int it = 0; it < 3; ++it) {
            int idx = it * 256 + tid;
            if (idx < 640) {
                int c4 = idx / 160;            // 0..3
                int r2 = idx - c4 * 160;       // 0..159
                int yy = r2 / 20, xx = r2 - yy * 20;
                int gy = ty0 - 2 + yy, gx = tx0 - 2 + xx;
                f32x4 st = {0.f, 0.f, 0.f, 0.f};
                if (gy >= 0 && gy < 64 && gx >= 0 && gx < 64) {
                    size_t base = (size_t)(cbase + c4 * 4) * HW_ + (gy << 6) + gx;
                    st[0] = xb[base];
                    st[1] = xb[base + HW_];
                    st[2] = xb[base + 2 * HW_];
                    st[3] = xb[base + 3 * HW_];
                }
                *(f32x4*)&xt[r2 * 20 + c4 * 4] = st;
            }
        }
        __syncthreads();

        float acc[16];
#pragma unroll
        for (int e = 0; e < 16; ++e) acc[e] = 0.f;

#pragma unroll
        for (int dy = 0; dy < 5; ++dy)
#pragma unroll
            for (int dx = 0; dx < 5; ++dx) {
                int pxi = (py + dy) * 20 + pxx + dx;
                float wk = wgt[dy * 5 + dx];
#pragma unroll
                for (int c4 = 0; c4 < 4; ++c4) {
                    f32x4 xv = *(const f32x4*)&xt[pxi * 20 + c4 * 4];
                    acc[c4 * 4 + 0] = fmaf(wk, xv[0], acc[c4 * 4 + 0]);
                    acc[c4 * 4 + 1] = fmaf(wk, xv[1], acc[c4 * 4 + 1]);
                    acc[c4 * 4 + 2] = fmaf(wk, xv[2], acc[c4 * 4 + 2]);
                    acc[c4 * 4 + 3] = fmaf(wk, xv[3], acc[c4 * 4 + 3]);
                }
            }
#pragma unroll
        for (int e = 0; e < 16; ++e)
            op[(size_t)(cbase + e) * 16384] = acc[e];
    }
}

extern "C" void kernel_launch(void* const* d_in, const int* in_sizes, int n_in,
                              void* d_out, int out_size, void* d_ws, size_t ws_size,
                              hipStream_t stream) {
    const float* x      = (const float*)d_in[0];
    const float* comp_w = (const float*)d_in[1];
    const float* comp_g = (const float*)d_in[2];
    const float* comp_b = (const float*)d_in[3];
    const float* enc_w  = (const float*)d_in[4];
    const float* enc_g  = (const float*)d_in[5];
    const float* enc_b  = (const float*)d_in[6];
    float* out = (float*)d_out;

    float* ws = (float*)d_ws;
    __bf16* t1c = (__bf16*)ws;             // 8*4096*64 bf16 = 4 MB
    float* t2c  = ws + 1048576;            // 8*4096*112 fp32 = 14.7 MB
    float* st   = ws + 1048576 + 3670016;
    float* csum = st;                      // 64
    float* csq  = st + 64;                 // 64
    float* esum = st + 128;                // 112
    float* esq  = st + 240;                // 112
    __bf16* wprep = (__bf16*)(st + 352);   // 112*576 bf16

    hipMemsetAsync(st, 0, 352 * sizeof(float), stream);
    k_conv1<<<512, 256, 0, stream>>>(x, comp_w, enc_w, t1c, csum, csq, wprep);
    k_conv3<<<512, 256, 0, stream>>>(t1c, wprep, csum, csq, comp_g, comp_b, t2c, esum, esq);
    k_carafe<<<512, 256, 0, stream>>>(x, t2c, esum, esq, enc_g, enc_b, out);
}

// Round 9
// 154.020 us; speedup vs baseline: 3.1228x; 1.1589x over previous
//
#include <hip/hip_runtime.h>
#include <hip/hip_bf16.h>
#include <math.h>

#define C_   128
#define HW_  4096
#define OC_  100
#define NSTAT_ 32768.0f

typedef __bf16 bf16x8 __attribute__((ext_vector_type(8)));
typedef __bf16 bf16x4 __attribute__((ext_vector_type(4)));
typedef float  f32x4  __attribute__((ext_vector_type(4)));

// ---------------- K1: 1x1 conv via MFMA bf16 -> t1c[b][px][64] bf16 + stats + wprep --------
// grid 512 = b(8) x chunk(64 of 64px); 256 thr = 4 waves, wave = one 16-px m-tile, N=64.
__global__ __launch_bounds__(256, 4) void k_conv1(const float* __restrict__ x,
                                                  const float* __restrict__ w,
                                                  const float* __restrict__ wenc,
                                                  __bf16* __restrict__ t1c,
                                                  float* __restrict__ csum,
                                                  float* __restrict__ csq,
                                                  __bf16* __restrict__ wprep) {
    __shared__ __bf16 xt[64 * 128];   // [px][ic], 256B rows, 16B-block XOR swizzle
    __shared__ __bf16 wt[64 * 128];   // [oc][ic], same swizzle
    __shared__ float sS[64], sQ[64];

    int blk = blockIdx.x;
    int b = blk & 7;
    int chunk = blk >> 3;             // 0..63
    int px0 = chunk * 64;
    int tid = threadIdx.x;
    if (tid < 64) { sS[tid] = 0.f; sQ[tid] = 0.f; }

    // pack enc weights -> wprep[oc 112][k 576], k = tap*64+ic  (blocks 0..62, 1024 each)
    if (blk < 63) {
#pragma unroll
        for (int u = 0; u < 4; ++u) {
            int idx = blk * 1024 + u * 256 + tid;   // < 64512 = 112*576
            int oc = idx / 576, k = idx - oc * 576;
            int tap = k >> 6, ic = k & 63;
            wprep[idx] = (oc < OC_) ? (__bf16)wenc[((size_t)oc * 64 + ic) * 9 + tap]
                                    : (__bf16)0.f;
        }
    }

    // stage comp_w (64 oc x 128 ic fp32) -> wt bf16: 2048 float4 jobs
#pragma unroll
    for (int it = 0; it < 8; ++it) {
        int j = it * 256 + tid;       // 0..2047
        int oc = j >> 5, f = j & 31;
        float4 v = *(const float4*)(w + (size_t)oc * 128 + f * 4);
        int blki = (f >> 1) ^ (oc & 15);
        bf16x4 st;
        st[0] = (__bf16)v.x; st[1] = (__bf16)v.y; st[2] = (__bf16)v.z; st[3] = (__bf16)v.w;
        *(bf16x4*)&wt[oc * 128 + blki * 8 + (f & 1) * 4] = st;
    }
    // stage x tile (64 px x 128 ic) -> xt bf16 (transpose 4x4 in regs), 512 jobs x 16 floats
#pragma unroll
    for (int it = 0; it < 2; ++it) {
        int j = it * 256 + tid;
        int px4 = (j & 15) * 4, icq = j >> 4;   // icq 0..31
        const float* xp = x + ((size_t)b * C_ + icq * 4) * HW_ + px0 + px4;
        float4 v0 = *(const float4*)(xp);
        float4 v1 = *(const float4*)(xp + HW_);
        float4 v2 = *(const float4*)(xp + 2 * HW_);
        float4 v3 = *(const float4*)(xp + 3 * HW_);
        float r0[4] = {v0.x, v0.y, v0.z, v0.w};
        float r1[4] = {v1.x, v1.y, v1.z, v1.w};
        float r2_[4] = {v2.x, v2.y, v2.z, v2.w};
        float r3[4] = {v3.x, v3.y, v3.z, v3.w};
#pragma unroll
        for (int r2 = 0; r2 < 4; ++r2) {
            int px = px4 + r2;
            int blki = (icq >> 1) ^ (px & 15);
            bf16x4 st;
            st[0] = (__bf16)r0[r2]; st[1] = (__bf16)r1[r2];
            st[2] = (__bf16)r2_[r2]; st[3] = (__bf16)r3[r2];
            *(bf16x4*)&xt[px * 128 + blki * 8 + (icq & 1) * 4] = st;
        }
    }
    __syncthreads();

    int lane = tid & 63, wv = tid >> 6;
    int p = lane & 15, q = lane >> 4;

    f32x4 acc[4];
#pragma unroll
    for (int n = 0; n < 4; ++n) acc[n] = (f32x4){0.f, 0.f, 0.f, 0.f};

#pragma unroll
    for (int kk = 0; kk < 4; ++kk) {
        int blki = (kk * 4 + q) ^ p;
        bf16x8 a = *(const bf16x8*)&xt[(wv * 16 + p) * 128 + blki * 8];
#pragma unroll
        for (int n = 0; n < 4; ++n) {
            bf16x8 bb = *(const bf16x8*)&wt[(n * 16 + p) * 128 + blki * 8];
            acc[n] = __builtin_amdgcn_mfma_f32_16x16x32_bf16(a, bb, acc[n], 0, 0, 0);
        }
    }

    // D: col(oc within tile) = p, row(px within tile) = q*4+rg
    __bf16* t1b = t1c + ((size_t)b * HW_ + px0 + wv * 16) * 64;
#pragma unroll
    for (int n = 0; n < 4; ++n) {
        float s = 0.f, qq = 0.f;
#pragma unroll
        for (int rg = 0; rg < 4; ++rg) {
            float v = acc[n][rg];
            t1b[(size_t)(q * 4 + rg) * 64 + n * 16 + p] = (__bf16)v;
            s += v; qq += v * v;
        }
        s += __shfl_down(s, 32, 64);  s += __shfl_down(s, 16, 64);
        qq += __shfl_down(qq, 32, 64); qq += __shfl_down(qq, 16, 64);
        if (lane < 16) {
            atomicAdd(&sS[n * 16 + p], s);
            atomicAdd(&sQ[n * 16 + p], qq);
        }
    }
    __syncthreads();
    if (tid < 64) {
        atomicAdd(&csum[tid], sS[tid]);
        atomicAdd(&csq[tid], sQ[tid]);
    }
}

// ---------------- K2: 3x3 conv MFMA; B-operand through double-buffered LDS ----------------
// grid 512 = b(8) x tile(64 of 8x8 px); 256 thr = 4 waves.
__global__ __launch_bounds__(256, 4) void k_conv3(const __bf16* __restrict__ t1c,
                                                  const __bf16* __restrict__ wprep,
                                                  const float* __restrict__ csum,
                                                  const float* __restrict__ csq,
                                                  const float* __restrict__ cg,
                                                  const float* __restrict__ cb,
                                                  float* __restrict__ t2c,
                                                  float* __restrict__ esum,
                                                  float* __restrict__ esq) {
    __shared__ __bf16 xt[10 * 10 * 72];        // 14400 B
    __shared__ __bf16 bt[2][112 * 32];         // [buf][oc][32k] = 2 x 7168 B
    __shared__ float lsc[64], lsh[64];
    __shared__ float esuml[112], esql[112];

    int blk = blockIdx.x;
    int b = blk & 7;
    int tile = blk >> 3;
    int ty0 = (tile >> 3) * 8, tx0 = (tile & 7) * 8;
    int tid = threadIdx.x;
    if (tid < 112) { esuml[tid] = 0.f; esql[tid] = 0.f; }
    if (tid >= 128 && tid < 192) {
        int c = tid - 128;
        float invN = 1.0f / NSTAT_;
        float m = csum[c] * invN;
        float v = csq[c] * invN - m * m;
        float rs = rsqrtf(v + 1e-5f);
        float sc = cg[c] * rs;
        lsc[c] = sc;
        lsh[c] = cb[c] - m * sc;
    }
    __syncthreads();   // lsc/lsh ready for staging

    // prologue: stage B chunk kk=0 into bt[0]  (448 chunks of 16B)
    {
        int oc = tid >> 2, part = tid & 3;
        *(bf16x8*)&bt[0][oc * 32 + part * 8] =
            *(const bf16x8*)(wprep + (size_t)oc * 576 + part * 8);
        if (tid < 192) {
            int c1 = tid + 256;
            int oc1 = c1 >> 2, p1 = c1 & 3;
            *(bf16x8*)&bt[0][oc1 * 32 + p1 * 8] =
                *(const bf16x8*)(wprep + (size_t)oc1 * 576 + p1 * 8);
        }
    }

    // stage BN+SiLU(t1) 10x10 halo -> xt  (1600 jobs of 4 ic)
    const __bf16* tb = t1c + (size_t)b * HW_ * 64;
#pragma unroll
    for (int it = 0; it < 7; ++it) {
        int idx = it * 256 + tid;
        if (idx < 1600) {
            int pxi = idx >> 4, f4 = idx & 15;
            int yy = pxi / 10, xx = pxi - yy * 10;
            int gy = ty0 + yy - 1, gx = tx0 + xx - 1;
            float o0 = 0.f, o1 = 0.f, o2 = 0.f, o3 = 0.f;
            if (gy >= 0 && gy < 64 && gx >= 0 && gx < 64) {
                bf16x4 v = *(const bf16x4*)(tb + ((size_t)(gy << 6) + gx) * 64 + f4 * 4);
                float4 sc = *(const float4*)(lsc + f4 * 4);
                float4 sh = *(const float4*)(lsh + f4 * 4);
                float u;
                u = fmaf((float)v[0], sc.x, sh.x); o0 = u / (1.f + __expf(-u));
                u = fmaf((float)v[1], sc.y, sh.y); o1 = u / (1.f + __expf(-u));
                u = fmaf((float)v[2], sc.z, sh.z); o2 = u / (1.f + __expf(-u));
                u = fmaf((float)v[3], sc.w, sh.w); o3 = u / (1.f + __expf(-u));
            }
            bf16x4 st;
            st[0] = (__bf16)o0; st[1] = (__bf16)o1; st[2] = (__bf16)o2; st[3] = (__bf16)o3;
            *(bf16x4*)&xt[pxi * 72 + f4 * 4] = st;
        }
    }
    __syncthreads();   // bt[0] + xt ready

    int lane = tid & 63, wv = tid >> 6;
    int p = lane & 15, q = lane >> 4;
    int ya = 2 * wv + (p >> 3), xa = p & 7;
    int soc = tid >> 2, spart = tid & 3;          // staging roles
    int soc1 = (tid + 256) >> 2, spart1 = (tid + 256) & 3;

    f32x4 acc[7];
#pragma unroll
    for (int n = 0; n < 7; ++n) acc[n] = (f32x4){0.f, 0.f, 0.f, 0.f};

#pragma unroll
    for (int kk = 0; kk < 18; ++kk) {
        const int cur = kk & 1;
        // prefetch B chunk kk+1 into regs (coalesced 16B loads, latency overlapped)
        bf16x8 r0, r1;
        if (kk < 17) {
            r0 = *(const bf16x8*)(wprep + (size_t)soc * 576 + (kk + 1) * 32 + spart * 8);
            if (tid < 192)
                r1 = *(const bf16x8*)(wprep + (size_t)soc1 * 576 + (kk + 1) * 32 + spart1 * 8);
        }
        // compute from bt[cur]
        const int tap = kk >> 1, ich = (kk & 1) * 32;
        const int ky = tap / 3, kx = tap - ky * 3;
        bf16x8 a0 = *(const bf16x8*)&xt[((ya + ky) * 10 + xa + kx) * 72 + ich + q * 8];
#pragma unroll
        for (int n = 0; n < 7; ++n) {
            bf16x8 bb = *(const bf16x8*)&bt[cur][(n * 16 + p) * 32 + q * 8];
            acc[n] = __builtin_amdgcn_mfma_f32_16x16x32_bf16(a0, bb, acc[n], 0, 0, 0);
        }
        // write prefetched chunk to the other buffer
        if (kk < 17) {
            *(bf16x8*)&bt[1 - cur][soc * 32 + spart * 8] = r0;
            if (tid < 192)
                *(bf16x8*)&bt[1 - cur][soc1 * 32 + spart1 * 8] = r1;
            __syncthreads();
        }
    }

    float* t2b = t2c + (size_t)b * HW_ * 112;
#pragma unroll
    for (int n = 0; n < 7; ++n) {
        float s = 0.f, qq = 0.f;
#pragma unroll
        for (int rg = 0; rg < 4; ++rg) {
            int mp = q * 4 + rg;
            int y = ty0 + 2 * wv + (mp >> 3), xo = tx0 + (mp & 7);
            float v = acc[n][rg];
            t2b[((size_t)y * 64 + xo) * 112 + n * 16 + p] = v;
            s += v; qq += v * v;
        }
        s += __shfl_down(s, 32, 64);  s += __shfl_down(s, 16, 64);
        qq += __shfl_down(qq, 32, 64); qq += __shfl_down(qq, 16, 64);
        if (lane < 16) {
            atomicAdd(&esuml[n * 16 + lane], s);
            atomicAdd(&esql[n * 16 + lane], qq);
        }
    }
    __syncthreads();
    if (tid < 112) {
        atomicAdd(&esum[tid], esuml[tid]);
        atomicAdd(&esq[tid], esql[tid]);
    }
}

// ---------------- K3: BN2 + softmax + reassembly; reg-prefetch + LDS double buffer --------
// grid 1024 = b(8) x tile(64: 16w x 4t lowres) x chalf(2 of 64ch); 256 thr = 64px x 4 subpx.
// 4 stages of 16 ch. Thread state: wgt[25]+acc[16]+pf[3] (~76 VGPR, no spill).
__global__ __launch_bounds__(256, 4) void k_carafe(const float* __restrict__ x,
                                                   const float* __restrict__ t2c,
                                                   const float* __restrict__ esum,
                                                   const float* __restrict__ esq,
                                                   const float* __restrict__ eg,
                                                   const float* __restrict__ eb,
                                                   float* __restrict__ out) {
    __shared__ float xt[2][160 * 20];  // [buf][halo px 8x20][16 ch pad 20] = 2 x 12800 B
    __shared__ float esc[112], esh[112];

    int blk = blockIdx.x;
    int b = blk & 7;
    int r = blk >> 3;
    int tile = r & 63;
    int chalf = r >> 6;
    int tx0 = (tile & 3) * 16, ty0 = (tile >> 2) * 4;
    int tid = threadIdx.x;
    if (tid < 112) {
        float invN = 1.0f / NSTAT_;
        float m = esum[tid] * invN;
        float v = esq[tid] * invN - m * m;
        float rs = rsqrtf(v + 1e-5f);
        float sc = (tid < OC_) ? eg[tid] * rs : 0.f;
        esc[tid] = sc;
        esh[tid] = (tid < OC_) ? eb[tid] - m * sc : 0.f;
    }
    __syncthreads();

    int s = tid & 3, px = tid >> 2;
    int pxx = px & 15, py = px >> 4;
    int iy = ty0 + py, jx = tx0 + pxx;

    float wgt[25];
    {
        const float* t2p = t2c + ((size_t)((b << 12) + (iy << 6) + jx)) * 112 + s;
        float mx = -1e30f;
#pragma unroll
        for (int k = 0; k < 25; ++k) {
            float l = fmaf(t2p[k * 4], esc[4 * k + s], esh[4 * k + s]);
            wgt[k] = l;
            mx = fmaxf(mx, l);
        }
        float sum = 0.f;
#pragma unroll
        for (int k = 0; k < 25; ++k) {
            float e = __expf(wgt[k] - mx);
            wgt[k] = e;
            sum += e;
        }
        float inv = 1.f / sum;
#pragma unroll
        for (int k = 0; k < 25; ++k) wgt[k] *= inv;
    }

    const float* xb = x + (size_t)b * C_ * HW_;
    int i0 = iy * 2 + (s >> 1), j0 = jx * 2 + (s & 1);
    float* op = out + (size_t)b * C_ * 16384 + (size_t)i0 * 128 + j0;

    // staging roles (shared by prologue + prefetch): 640 jobs, 3 rounds
    int sidx[3], sgy[3], sgx[3], sc4[3];
#pragma unroll
    for (int it = 0; it < 3; ++it) {
        int idx = it * 256 + tid;
        sidx[it] = idx;
        int c4 = idx / 160;
        int r2 = idx - c4 * 160;
        int yy = r2 / 20, xx = r2 - yy * 20;
        sgy[it] = ty0 - 2 + yy;
        sgx[it] = tx0 - 2 + xx;
        sc4[it] = c4;
    }

    // prologue: stage 0 directly into xt[0]
#pragma unroll
    for (int it = 0; it < 3; ++it) {
        if (sidx[it] < 640) {
            int gy = sgy[it], gx = sgx[it];
            f32x4 st = {0.f, 0.f, 0.f, 0.f};
            if (gy >= 0 && gy < 64 && gx >= 0 && gx < 64) {
                size_t base = (size_t)(chalf * 64 + sc4[it] * 4) * HW_ + (gy << 6) + gx;
                st[0] = xb[base];
                st[1] = xb[base + HW_];
                st[2] = xb[base + 2 * HW_];
                st[3] = xb[base + 3 * HW_];
            }
            int r2 = sidx[it] - sc4[it] * 160;
            *(f32x4*)&xt[0][r2 * 20 + sc4[it] * 4] = st;
        }
    }

#pragma unroll
    for (int stage = 0; stage < 4; ++stage) {
        int cur = stage & 1;
        int cbase = chalf * 64 + stage * 16;
        // prefetch next stage's channels into regs
        f32x4 pf[3];
        if (stage < 3) {
#pragma unroll
            for (int it = 0; it < 3; ++it) {
                if (sidx[it] < 640) {
                    int gy = sgy[it], gx = sgx[it];
                    f32x4 st = {0.f, 0.f, 0.f, 0.f};
                    if (gy >= 0 && gy < 64 && gx >= 0 && gx < 64) {
                        size_t base = (size_t)(cbase + 16 + sc4[it] * 4) * HW_ + (gy << 6) + gx;
                        st[0] = xb[base];
                        st[1] = xb[base + HW_];
                        st[2] = xb[base + 2 * HW_];
                        st[3] = xb[base + 3 * HW_];
                    }
                    pf[it] = st;
                }
            }
        }
        __syncthreads();   // xt[cur] ready

        float acc[16];
#pragma unroll
        for (int e = 0; e < 16; ++e) acc[e] = 0.f;
#pragma unroll
        for (int dy = 0; dy < 5; ++dy)
#pragma unroll
            for (int dx = 0; dx < 5; ++dx) {
                int pxi = (py + dy) * 20 + pxx + dx;
                float wk = wgt[dy * 5 + dx];
#pragma unroll
                for (int c4 = 0; c4 < 4; ++c4) {
                    f32x4 xv = *(const f32x4*)&xt[cur][pxi * 20 + c4 * 4];
                    acc[c4 * 4 + 0] = fmaf(wk, xv[0], acc[c4 * 4 + 0]);
                    acc[c4 * 4 + 1] = fmaf(wk, xv[1], acc[c4 * 4 + 1]);
                    acc[c4 * 4 + 2] = fmaf(wk, xv[2], acc[c4 * 4 + 2]);
                    acc[c4 * 4 + 3] = fmaf(wk, xv[3], acc[c4 * 4 + 3]);
                }
            }
#pragma unroll
        for (int e = 0; e < 16; ++e)
            op[(size_t)(cbase + e) * 16384] = acc[e];

        if (stage < 3) {
#pragma unroll
            for (int it = 0; it < 3; ++it) {
                if (sidx[it] < 640) {
                    int r2 = sidx[it] - sc4[it] * 160;
                    *(f32x4*)&xt[1 - cur][r2 * 20 + sc4[it] * 4] = pf[it];
                }
            }
        }
    }
}

extern "C" void kernel_launch(void* const* d_in, const int* in_sizes, int n_in,
                              void* d_out, int out_size, void* d_ws, size_t ws_size,
                              hipStream_t stream) {
    const float* x      = (const float*)d_in[0];
    const float* comp_w = (const float*)d_in[1];
    const float* comp_g = (const float*)d_in[2];
    const float* comp_b = (const float*)d_in[3];
    const float* enc_w  = (const float*)d_in[4];
    const float* enc_g  = (const float*)d_in[5];
    const float* enc_b  = (const float*)d_in[6];
    float* out = (float*)d_out;

    float* ws = (float*)d_ws;
    __bf16* t1c = (__bf16*)ws;             // 8*4096*64 bf16 = 4 MB
    float* t2c  = ws + 1048576;            // 8*4096*112 fp32 = 14.7 MB
    float* st   = ws + 1048576 + 3670016;
    float* csum = st;                      // 64
    float* csq  = st + 64;                 // 64
    float* esum = st + 128;                // 112
    float* esq  = st + 240;                // 112
    __bf16* wprep = (__bf16*)(st + 352);   // 112*576 bf16

    hipMemsetAsync(st, 0, 352 * sizeof(float), stream);
    k_conv1<<<512, 256, 0, stream>>>(x, comp_w, enc_w, t1c, csum, csq, wprep);
    k_conv3<<<512, 256, 0, stream>>>(t1c, wprep, csum, csq, comp_g, comp_b, t2c, esum, esq);
    k_carafe<<<1024, 256, 0, stream>>>(x, t2c, esum, esq, enc_g, enc_b, out);
}